// Round 2
// baseline (423.696 us; speedup 1.0000x reference)
//
#include <hip/hip_runtime.h>

// GAT layer: N=8192, IN_DIM=128, OUT_DIM=64, alpha=0.2
// out = elu( softmax_row( mask(lrelu(s1_i + s2_j), adj) ) @ Wh )
//
// R6b: R6 with compile fix (ext_vector int4 for nontemporal builtin).
//  - peel last adj prefetch (wrap reload was +12.5% on the 256-MB adj read)
//  - prefetch next tile's s2L float4 with the adj prefetch (hide L2 latency)
//  - one-ahead A-frag ds_read pipeline (hide LDS latency under MFMA)
//  - adj loads non-temporal: zero-reuse stream, keep Bpack/s2L L2-resident
//  - wh_kernel: 4 rows/block, 256 thr (8192 -> 2048 blocks, no barrier)
//  - max_kernel folded into bpack_kernel as one extra block (one less launch)

#define N 8192
#define IN_DIM 128
#define OUT_DIM 64
#define ALPHA 0.2f
#define LOG2E 1.44269504088896f
#define JC 8             // j-chunks
#define CW (N / JC)      // 1024 cols per chunk
#define TW 128           // cols per tile
#define NT (CW / TW)     // 8 tiles
#define LDP 136          // LDS row stride (halfs)

typedef _Float16 half8 __attribute__((ext_vector_type(8)));
typedef _Float16 half4 __attribute__((ext_vector_type(4)));
typedef float f32x4 __attribute__((ext_vector_type(4)));
typedef int i32x4 __attribute__((ext_vector_type(4)));  // clang vec: NT-load ok

// ---------------------------------------------------------------------------
// Kernel 1: Wh = x@W (fp16, transposed [f][i]); s1L/s2L = log2e * scores
// 4 rows per block, one wave per row, per-wave LDS slice (no barrier).
// ---------------------------------------------------------------------------
__global__ __launch_bounds__(256) void wh_kernel(
    const float* __restrict__ x, const float* __restrict__ W,
    const float* __restrict__ a, _Float16* __restrict__ Wh_t,
    float* __restrict__ s1L, float* __restrict__ s2L) {
  __shared__ float xs[4][IN_DIM];
  const int w = threadIdx.x >> 6;
  const int t = threadIdx.x & 63;  // output feature f
  const int i = blockIdx.x * 4 + w;

  xs[w][t] = x[(size_t)i * IN_DIM + t];
  xs[w][t + 64] = x[(size_t)i * IN_DIM + 64 + t];
  // same-wave LDS RAW: in-order DS pipe + compiler lgkmcnt, no barrier needed

  float wh = 0.f;
#pragma unroll
  for (int d = 0; d < IN_DIM; ++d) wh = fmaf(xs[w][d], W[d * OUT_DIM + t], wh);

  Wh_t[(size_t)t * N + i] = (_Float16)wh;

  float p1 = wh * a[t];
  float p2 = wh * a[64 + t];
#pragma unroll
  for (int off = 32; off; off >>= 1) {
    p1 += __shfl_down(p1, off);
    p2 += __shfl_down(p2, off);
  }
  if (t == 0) {
    s1L[i] = p1 * LOG2E;
    s2L[i] = p2 * LOG2E;
  }
}

// ---------------------------------------------------------------------------
// Kernel 2: pack B-fragments; block N/32 additionally computes
// c0 = exp2(-ML), ML = lrelu(max(s1L)+max(s2L)) (scaled domain).
// Global bound -> p = exp2(uu)*c0 <= 1: fp16-safe, ratios exact,
// j-associative. exp2(uu) <= exp2(ML) ~ 600, no f32 overflow.
// ---------------------------------------------------------------------------
__global__ __launch_bounds__(256) void bpack_kernel(
    const _Float16* __restrict__ Wh_t, _Float16* __restrict__ Bpack,
    const float* __restrict__ s1L, const float* __restrict__ s2L,
    float* __restrict__ c0out) {
  if (blockIdx.x == N / 32) {
    // ---- max/normalizer block (was max_kernel) ----
    __shared__ float red[8];
    const int t = threadIdx.x;
    float m1 = -1e30f, m2 = -1e30f;
    for (int idx = t; idx < N; idx += 256) {
      m1 = fmaxf(m1, s1L[idx]);
      m2 = fmaxf(m2, s2L[idx]);
    }
#pragma unroll
    for (int off = 32; off; off >>= 1) {
      m1 = fmaxf(m1, __shfl_down(m1, off));
      m2 = fmaxf(m2, __shfl_down(m2, off));
    }
    if ((t & 63) == 0) {
      red[t >> 6] = m1;
      red[4 + (t >> 6)] = m2;
    }
    __syncthreads();
    if (t == 0) {
      m1 = fmaxf(fmaxf(red[0], red[1]), fmaxf(red[2], red[3]));
      m2 = fmaxf(fmaxf(red[4], red[5]), fmaxf(red[6], red[7]));
      float e = m1 + m2;
      c0out[0] = exp2f(-fmaxf(e, ALPHA * e));
    }
    return;
  }

  // ---- B-fragment packing ----
  // Bpack[((kt*4+fg)*64+lane)*8 ..] = Wh_t[fg*16+r16][kt*32+q*8..+7]
  const int kt = blockIdx.x;  // 0..255 (32-wide k steps)
  const int t = threadIdx.x;
  const int fg = t >> 6;
  const int lane = t & 63;
  const int q = (t >> 4) & 3;
  const int r16 = t & 15;
  const half8 v =
      *(const half8*)(Wh_t + (size_t)(fg * 16 + r16) * N + kt * 32 + q * 8);
  *(half8*)(Bpack + ((size_t)(kt * 4 + fg) * 64 + lane) * 8) = v;
}

// ---------------------------------------------------------------------------
// Kernel 3: fused adj streamer. grid (N/64, JC), 4 waves; wave w: rows
// i0..i0+15, cols [c*1024,+1024) in 8 tiles of 128. All global loads
// lane-contiguous. Per-wave LDS for the A-frag layout change; no barriers.
// ---------------------------------------------------------------------------
__global__ __launch_bounds__(256, 4) void attn_kernel(
    const int* __restrict__ adj, const _Float16* __restrict__ Bpack,
    const float* __restrict__ s1L, const float* __restrict__ s2L,
    const float* __restrict__ c0p, float* __restrict__ accp,
    float* __restrict__ lp) {
  __shared__ __align__(16) _Float16 Ps[4 * 16 * LDP];

  const int t = threadIdx.x;
  const int w = t >> 6;
  const int lane = t & 63;
  const int q = lane >> 4;
  const int r16 = lane & 15;
  const int half_ = lane >> 5;  // which row of the 2-row load pair
  const int l32 = lane & 31;    // position in the 512-B row segment
  const int rb = (int)(gridDim.x - 1 - blockIdx.x);  // reverse: tail rows hot
  const int i0 = rb * 64 + w * 16;
  const int c = blockIdx.y;
  const int jb = c * CW;

  const float c0 = c0p[0];

  float s1v8[8];
#pragma unroll
  for (int it = 0; it < 8; ++it) s1v8[it] = s1L[i0 + 2 * it + half_];

  half8 bones;
#pragma unroll
  for (int e = 0; e < 8; ++e)
    bones[e] = (r16 == 0) ? (_Float16)1.0f : (_Float16)0.0f;

  f32x4 acc[5] = {{0.f, 0.f, 0.f, 0.f}, {0.f, 0.f, 0.f, 0.f},
                  {0.f, 0.f, 0.f, 0.f}, {0.f, 0.f, 0.f, 0.f},
                  {0.f, 0.f, 0.f, 0.f}};

  const int* aprow = adj + (size_t)(i0 + half_) * N + jb + l32 * 4;
  _Float16* Pw = Ps + w * 16 * LDP;
  const _Float16* ldA = Pw + r16 * LDP + q * 8;
  _Float16* stP = Pw + half_ * LDP + l32 * 4;

  // preload tile 0 (adj non-temporal: zero-reuse stream)
  i32x4 av[8];
#pragma unroll
  for (int it = 0; it < 8; ++it)
    av[it] = __builtin_nontemporal_load(
        (const i32x4*)(aprow + (size_t)(2 * it) * N));
  float4 sv = *(const float4*)(s2L + jb + l32 * 4);

  for (int jt = 0; jt < NT; ++jt) {
    const bool more = (jt + 1 < NT);  // peeled: no wrap reload of tile 0

    // prefetch next tile's adj + s2L (independent, in flight through compute)
    i32x4 nv[8];
    float4 svn;
    if (more) {
      const int joff_next = (jt + 1) * TW;
#pragma unroll
      for (int it = 0; it < 8; ++it)
        nv[it] = __builtin_nontemporal_load(
            (const i32x4*)(aprow + joff_next + (size_t)(2 * it) * N));
      svn = *(const float4*)(s2L + jb + joff_next + l32 * 4);
    }

    // P tile -> per-wave LDS (fp16). 7 VALU/elem: add,mul,max,exp2,mul,sel,cvt
#pragma unroll
    for (int it = 0; it < 8; ++it) {
      const float s1v = s1v8[it];
      float tt, uu;
      half4 hv;
      tt = s1v + sv.x; uu = fmaxf(tt, ALPHA * tt);
      hv[0] = (_Float16)(av[it].x != 0 ? exp2f(uu) * c0 : 0.f);
      tt = s1v + sv.y; uu = fmaxf(tt, ALPHA * tt);
      hv[1] = (_Float16)(av[it].y != 0 ? exp2f(uu) * c0 : 0.f);
      tt = s1v + sv.z; uu = fmaxf(tt, ALPHA * tt);
      hv[2] = (_Float16)(av[it].z != 0 ? exp2f(uu) * c0 : 0.f);
      tt = s1v + sv.w; uu = fmaxf(tt, ALPHA * tt);
      hv[3] = (_Float16)(av[it].w != 0 ? exp2f(uu) * c0 : 0.f);
      *(half4*)(stP + (2 * it) * LDP) = hv;
    }

    // MFMA: A from LDS (same-wave order guarantees no hazard), B from Bpack.
    // One-ahead ds_read pipeline: A-frag ks+1 in flight under ks's MFMAs.
    const int ktb = c * 32 + jt * 4;  // global 32-k-step index base
    half8 aF = *(const half8*)(ldA);
#pragma unroll
    for (int ks = 0; ks < 4; ++ks) {
      half8 aFn;
      if (ks < 3) aFn = *(const half8*)(ldA + (ks + 1) * 32);
      const _Float16* bp = Bpack + ((size_t)(ktb + ks) * 4 * 64 + lane) * 8;
#pragma unroll
      for (int fg = 0; fg < 4; ++fg) {
        const half8 bf = *(const half8*)(bp + (size_t)fg * 64 * 8);
        acc[fg] =
            __builtin_amdgcn_mfma_f32_16x16x32_f16(aF, bf, acc[fg], 0, 0, 0);
      }
      acc[4] =
          __builtin_amdgcn_mfma_f32_16x16x32_f16(aF, bones, acc[4], 0, 0, 0);
      if (ks < 3) aF = aFn;
    }

    if (more) {
#pragma unroll
      for (int it = 0; it < 8; ++it) av[it] = nv[it];
      sv = svn;
    }
  }

  // store partials. C/D: row = q*4+r, col = r16 (per fg block)
#pragma unroll
  for (int fg = 0; fg < 4; ++fg) {
#pragma unroll
    for (int r = 0; r < 4; ++r) {
      accp[((size_t)c * N + i0 + q * 4 + r) * OUT_DIM + fg * 16 + r16] =
          acc[fg][r];
    }
  }
  if (r16 == 0) {
#pragma unroll
    for (int r = 0; r < 4; ++r) lp[(size_t)c * N + i0 + q * 4 + r] = acc[4][r];
  }
}

// ---------------------------------------------------------------------------
// Kernel 4: combine JC partials, normalize, ELU.
// ---------------------------------------------------------------------------
__global__ __launch_bounds__(256) void reduce_kernel(
    const float* __restrict__ accp, const float* __restrict__ lp,
    float* __restrict__ out) {
  const int tid = blockIdx.x * 256 + threadIdx.x;  // over N*OUT_DIM
  const int i = tid >> 6;                          // row
  float s = 0.f, l = 0.f;
#pragma unroll
  for (int c = 0; c < JC; ++c) s += accp[(size_t)c * N * OUT_DIM + tid];
#pragma unroll
  for (int c = 0; c < JC; ++c) l += lp[(size_t)c * N + i];
  float v = s / l;
  out[tid] = v > 0.f ? v : expm1f(v);
}

// ---------------------------------------------------------------------------
extern "C" void kernel_launch(void* const* d_in, const int* in_sizes, int n_in,
                              void* d_out, int out_size, void* d_ws,
                              size_t ws_size, hipStream_t stream) {
  const float* x = (const float*)d_in[0];
  const int* adj = (const int*)d_in[1];
  const float* W = (const float*)d_in[2];
  const float* a = (const float*)d_in[3];
  float* out = (float*)d_out;

  char* ws = (char*)d_ws;
  _Float16* Wh_t = (_Float16*)ws;                  // 1 MiB
  float* s1L = (float*)(ws + (1u << 20));          // 32 KiB
  float* s2L = s1L + N;                            // 32 KiB
  float* c0 = s2L + N;                             // 4 B
  _Float16* Bpack = (_Float16*)(ws + (2u << 20));  // 1 MiB
  float* accp = (float*)(ws + (4u << 20));         // JC*N*64*4 = 16 MiB
  float* lp = accp + (size_t)JC * N * OUT_DIM;     // 256 KiB

  wh_kernel<<<N / 4, 256, 0, stream>>>(x, W, a, Wh_t, s1L, s2L);
  bpack_kernel<<<N / 32 + 1, 256, 0, stream>>>(Wh_t, Bpack, s1L, s2L, c0);
  attn_kernel<<<dim3(N / 64, JC), 256, 0, stream>>>(adj, Bpack, s1L, s2L, c0,
                                                    accp, lp);
  reduce_kernel<<<N * OUT_DIM / 256, 256, 0, stream>>>(accp, lp, out);
}

// Round 3
// 415.544 us; speedup vs baseline: 1.0196x; 1.0196x over previous
//
#include <hip/hip_runtime.h>

// GAT layer: N=8192, IN_DIM=128, OUT_DIM=64, alpha=0.2
// out = elu( softmax_row( mask(lrelu(s1_i + s2_j), adj) ) @ Wh )
//
// R7: R6b minus the two regression suspects.
//  - KEEP: peeled last prefetch (adj 288->256 MB, pure traffic cut)
//  - KEEP: s2L float4 prefetched with adj prefetch
//  - KEEP: wh_kernel 4 rows/block; max folded into bpack (fewer launches)
//  - REVERT: non-temporal adj loads -> plain int4 loads (R5 codegen)
//  - REVERT: A-frag one-ahead ds_read pipeline -> R5's simple per-ks read
//    (compiler already emits fine-grained lgkmcnt; source pipelining hurt)

#define N 8192
#define IN_DIM 128
#define OUT_DIM 64
#define ALPHA 0.2f
#define LOG2E 1.44269504088896f
#define JC 8             // j-chunks
#define CW (N / JC)      // 1024 cols per chunk
#define TW 128           // cols per tile
#define NT (CW / TW)     // 8 tiles
#define LDP 136          // LDS row stride (halfs)

typedef _Float16 half8 __attribute__((ext_vector_type(8)));
typedef _Float16 half4 __attribute__((ext_vector_type(4)));
typedef float f32x4 __attribute__((ext_vector_type(4)));

// ---------------------------------------------------------------------------
// Kernel 1: Wh = x@W (fp16, transposed [f][i]); s1L/s2L = log2e * scores
// 4 rows per block, one wave per row, per-wave LDS slice (no barrier).
// ---------------------------------------------------------------------------
__global__ __launch_bounds__(256) void wh_kernel(
    const float* __restrict__ x, const float* __restrict__ W,
    const float* __restrict__ a, _Float16* __restrict__ Wh_t,
    float* __restrict__ s1L, float* __restrict__ s2L) {
  __shared__ float xs[4][IN_DIM];
  const int w = threadIdx.x >> 6;
  const int t = threadIdx.x & 63;  // output feature f
  const int i = blockIdx.x * 4 + w;

  xs[w][t] = x[(size_t)i * IN_DIM + t];
  xs[w][t + 64] = x[(size_t)i * IN_DIM + 64 + t];
  // same-wave LDS RAW: in-order DS pipe + compiler lgkmcnt, no barrier needed

  float wh = 0.f;
#pragma unroll
  for (int d = 0; d < IN_DIM; ++d) wh = fmaf(xs[w][d], W[d * OUT_DIM + t], wh);

  Wh_t[(size_t)t * N + i] = (_Float16)wh;

  float p1 = wh * a[t];
  float p2 = wh * a[64 + t];
#pragma unroll
  for (int off = 32; off; off >>= 1) {
    p1 += __shfl_down(p1, off);
    p2 += __shfl_down(p2, off);
  }
  if (t == 0) {
    s1L[i] = p1 * LOG2E;
    s2L[i] = p2 * LOG2E;
  }
}

// ---------------------------------------------------------------------------
// Kernel 2: pack B-fragments; block N/32 additionally computes
// c0 = exp2(-ML), ML = lrelu(max(s1L)+max(s2L)) (scaled domain).
// Global bound -> p = exp2(uu)*c0 <= 1: fp16-safe, ratios exact,
// j-associative. exp2(uu) <= exp2(ML) ~ 600, no f32 overflow.
// ---------------------------------------------------------------------------
__global__ __launch_bounds__(256) void bpack_kernel(
    const _Float16* __restrict__ Wh_t, _Float16* __restrict__ Bpack,
    const float* __restrict__ s1L, const float* __restrict__ s2L,
    float* __restrict__ c0out) {
  if (blockIdx.x == N / 32) {
    // ---- max/normalizer block (was max_kernel) ----
    __shared__ float red[8];
    const int t = threadIdx.x;
    float m1 = -1e30f, m2 = -1e30f;
    for (int idx = t; idx < N; idx += 256) {
      m1 = fmaxf(m1, s1L[idx]);
      m2 = fmaxf(m2, s2L[idx]);
    }
#pragma unroll
    for (int off = 32; off; off >>= 1) {
      m1 = fmaxf(m1, __shfl_down(m1, off));
      m2 = fmaxf(m2, __shfl_down(m2, off));
    }
    if ((t & 63) == 0) {
      red[t >> 6] = m1;
      red[4 + (t >> 6)] = m2;
    }
    __syncthreads();
    if (t == 0) {
      m1 = fmaxf(fmaxf(red[0], red[1]), fmaxf(red[2], red[3]));
      m2 = fmaxf(fmaxf(red[4], red[5]), fmaxf(red[6], red[7]));
      float e = m1 + m2;
      c0out[0] = exp2f(-fmaxf(e, ALPHA * e));
    }
    return;
  }

  // ---- B-fragment packing ----
  // Bpack[((kt*4+fg)*64+lane)*8 ..] = Wh_t[fg*16+r16][kt*32+q*8..+7]
  const int kt = blockIdx.x;  // 0..255 (32-wide k steps)
  const int t = threadIdx.x;
  const int fg = t >> 6;
  const int lane = t & 63;
  const int q = (t >> 4) & 3;
  const int r16 = t & 15;
  const half8 v =
      *(const half8*)(Wh_t + (size_t)(fg * 16 + r16) * N + kt * 32 + q * 8);
  *(half8*)(Bpack + ((size_t)(kt * 4 + fg) * 64 + lane) * 8) = v;
}

// ---------------------------------------------------------------------------
// Kernel 3: fused adj streamer. grid (N/64, JC), 4 waves; wave w: rows
// i0..i0+15, cols [c*1024,+1024) in 8 tiles of 128. All global loads
// lane-contiguous. Per-wave LDS for the A-frag layout change; no barriers.
// ---------------------------------------------------------------------------
__global__ __launch_bounds__(256, 4) void attn_kernel(
    const int* __restrict__ adj, const _Float16* __restrict__ Bpack,
    const float* __restrict__ s1L, const float* __restrict__ s2L,
    const float* __restrict__ c0p, float* __restrict__ accp,
    float* __restrict__ lp) {
  __shared__ __align__(16) _Float16 Ps[4 * 16 * LDP];

  const int t = threadIdx.x;
  const int w = t >> 6;
  const int lane = t & 63;
  const int q = lane >> 4;
  const int r16 = lane & 15;
  const int half_ = lane >> 5;  // which row of the 2-row load pair
  const int l32 = lane & 31;    // position in the 512-B row segment
  const int rb = (int)(gridDim.x - 1 - blockIdx.x);  // reverse: tail rows hot
  const int i0 = rb * 64 + w * 16;
  const int c = blockIdx.y;
  const int jb = c * CW;

  const float c0 = c0p[0];

  float s1v8[8];
#pragma unroll
  for (int it = 0; it < 8; ++it) s1v8[it] = s1L[i0 + 2 * it + half_];

  half8 bones;
#pragma unroll
  for (int e = 0; e < 8; ++e)
    bones[e] = (r16 == 0) ? (_Float16)1.0f : (_Float16)0.0f;

  f32x4 acc[5] = {{0.f, 0.f, 0.f, 0.f}, {0.f, 0.f, 0.f, 0.f},
                  {0.f, 0.f, 0.f, 0.f}, {0.f, 0.f, 0.f, 0.f},
                  {0.f, 0.f, 0.f, 0.f}};

  const int* aprow = adj + (size_t)(i0 + half_) * N + jb + l32 * 4;
  _Float16* Pw = Ps + w * 16 * LDP;
  const _Float16* ldA = Pw + r16 * LDP + q * 8;
  _Float16* stP = Pw + half_ * LDP + l32 * 4;

  // preload tile 0
  int4 av[8];
#pragma unroll
  for (int it = 0; it < 8; ++it)
    av[it] = *(const int4*)(aprow + (size_t)(2 * it) * N);
  float4 sv = *(const float4*)(s2L + jb + l32 * 4);

  for (int jt = 0; jt < NT; ++jt) {
    const bool more = (jt + 1 < NT);  // peeled: no wrap reload of tile 0

    // prefetch next tile's adj + s2L (independent, in flight through compute)
    int4 nv[8];
    float4 svn;
    if (more) {
      const int joff_next = (jt + 1) * TW;
#pragma unroll
      for (int it = 0; it < 8; ++it)
        nv[it] = *(const int4*)(aprow + joff_next + (size_t)(2 * it) * N);
      svn = *(const float4*)(s2L + jb + joff_next + l32 * 4);
    }

    // P tile -> per-wave LDS (fp16). 7 VALU/elem: add,mul,max,exp2,mul,sel,cvt
#pragma unroll
    for (int it = 0; it < 8; ++it) {
      const float s1v = s1v8[it];
      float tt, uu;
      half4 hv;
      tt = s1v + sv.x; uu = fmaxf(tt, ALPHA * tt);
      hv[0] = (_Float16)(av[it].x != 0 ? exp2f(uu) * c0 : 0.f);
      tt = s1v + sv.y; uu = fmaxf(tt, ALPHA * tt);
      hv[1] = (_Float16)(av[it].y != 0 ? exp2f(uu) * c0 : 0.f);
      tt = s1v + sv.z; uu = fmaxf(tt, ALPHA * tt);
      hv[2] = (_Float16)(av[it].z != 0 ? exp2f(uu) * c0 : 0.f);
      tt = s1v + sv.w; uu = fmaxf(tt, ALPHA * tt);
      hv[3] = (_Float16)(av[it].w != 0 ? exp2f(uu) * c0 : 0.f);
      *(half4*)(stP + (2 * it) * LDP) = hv;
    }

    // MFMA: A from LDS (same-wave order guarantees no hazard), B from Bpack
    const int ktb = c * 32 + jt * 4;  // global 32-k-step index base
#pragma unroll
    for (int ks = 0; ks < 4; ++ks) {
      const half8 aF = *(const half8*)(ldA + ks * 32);
      const _Float16* bp = Bpack + ((size_t)(ktb + ks) * 4 * 64 + lane) * 8;
#pragma unroll
      for (int fg = 0; fg < 4; ++fg) {
        const half8 bf = *(const half8*)(bp + (size_t)fg * 64 * 8);
        acc[fg] =
            __builtin_amdgcn_mfma_f32_16x16x32_f16(aF, bf, acc[fg], 0, 0, 0);
      }
      acc[4] =
          __builtin_amdgcn_mfma_f32_16x16x32_f16(aF, bones, acc[4], 0, 0, 0);
    }

    if (more) {
#pragma unroll
      for (int it = 0; it < 8; ++it) av[it] = nv[it];
      sv = svn;
    }
  }

  // store partials. C/D: row = q*4+r, col = r16 (per fg block)
#pragma unroll
  for (int fg = 0; fg < 4; ++fg) {
#pragma unroll
    for (int r = 0; r < 4; ++r) {
      accp[((size_t)c * N + i0 + q * 4 + r) * OUT_DIM + fg * 16 + r16] =
          acc[fg][r];
    }
  }
  if (r16 == 0) {
#pragma unroll
    for (int r = 0; r < 4; ++r) lp[(size_t)c * N + i0 + q * 4 + r] = acc[4][r];
  }
}

// ---------------------------------------------------------------------------
// Kernel 4: combine JC partials, normalize, ELU.
// ---------------------------------------------------------------------------
__global__ __launch_bounds__(256) void reduce_kernel(
    const float* __restrict__ accp, const float* __restrict__ lp,
    float* __restrict__ out) {
  const int tid = blockIdx.x * 256 + threadIdx.x;  // over N*OUT_DIM
  const int i = tid >> 6;                          // row
  float s = 0.f, l = 0.f;
#pragma unroll
  for (int c = 0; c < JC; ++c) s += accp[(size_t)c * N * OUT_DIM + tid];
#pragma unroll
  for (int c = 0; c < JC; ++c) l += lp[(size_t)c * N + i];
  float v = s / l;
  out[tid] = v > 0.f ? v : expm1f(v);
}

// ---------------------------------------------------------------------------
extern "C" void kernel_launch(void* const* d_in, const int* in_sizes, int n_in,
                              void* d_out, int out_size, void* d_ws,
                              size_t ws_size, hipStream_t stream) {
  const float* x = (const float*)d_in[0];
  const int* adj = (const int*)d_in[1];
  const float* W = (const float*)d_in[2];
  const float* a = (const float*)d_in[3];
  float* out = (float*)d_out;

  char* ws = (char*)d_ws;
  _Float16* Wh_t = (_Float16*)ws;                  // 1 MiB
  float* s1L = (float*)(ws + (1u << 20));          // 32 KiB
  float* s2L = s1L + N;                            // 32 KiB
  float* c0 = s2L + N;                             // 4 B
  _Float16* Bpack = (_Float16*)(ws + (2u << 20));  // 1 MiB
  float* accp = (float*)(ws + (4u << 20));         // JC*N*64*4 = 16 MiB
  float* lp = accp + (size_t)JC * N * OUT_DIM;     // 256 KiB

  wh_kernel<<<N / 4, 256, 0, stream>>>(x, W, a, Wh_t, s1L, s2L);
  bpack_kernel<<<N / 32 + 1, 256, 0, stream>>>(Wh_t, Bpack, s1L, s2L, c0);
  attn_kernel<<<dim3(N / 64, JC), 256, 0, stream>>>(adj, Bpack, s1L, s2L, c0,
                                                    accp, lp);
  reduce_kernel<<<N * OUT_DIM / 256, 256, 0, stream>>>(accp, lp, out);
}